// Round 2
// baseline (1799.721 us; speedup 1.0000x reference)
//
#include <hip/hip_runtime.h>
#include <math.h>

// Problem constants (match reference)
#define BB 32
#define SS 128
#define II 64
#define HH 1024
#define TT 4
#define HQ (HH / 4)   // H in float4 units

constexpr float DECAY  = 0.9f;
constexpr float THRESH = 1.0f;
constexpr float BETA   = 5.0f;

typedef float f4 __attribute__((ext_vector_type(4)));

// -----------------------------------------------------------------------------
// Kernel 1: drive[b,s,h] = sum_i x[b,s,i,h] * enc[i,h]
//
// Page-sequential streaming layout: each WAVE owns a pair of bs rows. Each
// thread reads 64 B contiguous (4 consecutive float4) per (row, i), so one
// wave's 4-load burst covers exactly ONE 4 KB page (lane0 bytes [0,64),
// lane63 bytes [4032,4096)), and successive i walk pages sequentially.
// This replaces the previous pattern where every load instruction touched a
// different 4 KB page (4 KB stride), which is TLB/row-buffer hostile.
//
// Row-pair blocking: enc chunk loaded once per i, used for both rows
// (enc L2 traffic 0.5 GB). x loads are nontemporal (zero reuse stream).
// Result stashed in out[b, s*TT+3, h] (the t=3 slot lif reads strictly
// before overwriting). Workspace unused.
// -----------------------------------------------------------------------------
__global__ __launch_bounds__(256) void drive_kernel(
    const f4* __restrict__ x,      // [B*S, I, HQ]
    const f4* __restrict__ enc,    // [I, HQ]
    f4* __restrict__ out)          // [B, S*T, HQ]
{
    const int tid = blockIdx.x * blockDim.x + threadIdx.x;
    const int c   = tid & 63;          // 64B-chunk id within a row (one wave = one row-pair)
    const int g   = tid >> 6;          // row-pair id, [0, B*S/2)
    const int hq0 = c << 2;            // first of 4 consecutive f4 indices

    const f4* xa = x + ((size_t)(2 * g) * II) * HQ + hq0;       // row 2g
    const f4* xb = xa + (size_t)II * HQ;                        // row 2g+1
    const f4* ep = enc + hq0;

    f4 aa0 = {0.f,0.f,0.f,0.f}, aa1 = aa0, aa2 = aa0, aa3 = aa0;
    f4 ab0 = aa0, ab1 = aa0, ab2 = aa0, ab3 = aa0;

#pragma unroll 2
    for (int i = 0; i < II; ++i) {
        const f4* e  = ep + (size_t)i * HQ;
        const f4* pa = xa + (size_t)i * HQ;
        const f4* pb = xb + (size_t)i * HQ;
        f4 e0 = e[0], e1 = e[1], e2 = e[2], e3 = e[3];
        f4 a0 = __builtin_nontemporal_load(pa + 0);
        f4 a1 = __builtin_nontemporal_load(pa + 1);
        f4 a2 = __builtin_nontemporal_load(pa + 2);
        f4 a3 = __builtin_nontemporal_load(pa + 3);
        f4 b0 = __builtin_nontemporal_load(pb + 0);
        f4 b1 = __builtin_nontemporal_load(pb + 1);
        f4 b2 = __builtin_nontemporal_load(pb + 2);
        f4 b3 = __builtin_nontemporal_load(pb + 3);
        aa0 = __builtin_elementwise_fma(a0, e0, aa0);
        aa1 = __builtin_elementwise_fma(a1, e1, aa1);
        aa2 = __builtin_elementwise_fma(a2, e2, aa2);
        aa3 = __builtin_elementwise_fma(a3, e3, aa3);
        ab0 = __builtin_elementwise_fma(b0, e0, ab0);
        ab1 = __builtin_elementwise_fma(b1, e1, ab1);
        ab2 = __builtin_elementwise_fma(b2, e2, ab2);
        ab3 = __builtin_elementwise_fma(b3, e3, ab3);
    }

    // store both rows' results into the t=3 slots of out
    {
        const int bs = 2 * g;
        const int b  = bs >> 7;            // SS == 128
        const int s  = bs & (SS - 1);
        f4* d = out + ((size_t)b * SS * TT + (size_t)(s * TT + 3)) * HQ + hq0;
        d[0] = aa0; d[1] = aa1; d[2] = aa2; d[3] = aa3;
        f4* d2 = d + (size_t)TT * HQ;      // next s, same b (bs even => s<127)
        d2[0] = ab0; d2[1] = ab1; d2[2] = ab2; d2[3] = ab3;
    }
}

// -----------------------------------------------------------------------------
// Kernel 2: sequential LIF scan (unchanged from round 1 — verified correct).
// One thread per (b,h) chain. Depth-2 prefetch of the drive seeds from out's
// t=3 slots; sigmoid via v_exp_f32 + v_rcp_f32.
// -----------------------------------------------------------------------------
__global__ __launch_bounds__(64) void lif_kernel(
    float* __restrict__ out,       // [B, S*T, H]  (t=3 slots pre-seeded w/ drive)
    float* __restrict__ vfinal)    // [B, H]
{
    const int tid = blockIdx.x * blockDim.x + threadIdx.x;  // [0, B*H)
    const int h   = tid & (HH - 1);
    const int b   = tid >> 10;                              // H == 1024
    float* op = out + (size_t)b * SS * TT * HH + h;

    float v  = 0.f;
    float d0 = op[(size_t)3 * HH];                          // drive(s=0)
    float d1 = op[(size_t)7 * HH];                          // drive(s=1)

    for (int s = 0; s < SS; ++s) {
        float dn = 0.f;
        if (s + 2 < SS) dn = op[(size_t)((s + 2) * TT + 3) * HH];  // prefetch s+2
#pragma unroll
        for (int t = 0; t < TT; ++t) {
            v = fmaf(DECAY, v, d0);
            float az = fmaf(-BETA, v, BETA * THRESH);       // BETA*(THRESH - v)
            float e  = __expf(az);                          // exp(-BETA*(v-TH))
            float sp = __builtin_amdgcn_rcpf(1.f + e);      // sigmoid
            v = fmaf(-THRESH, sp, v);                       // subtractive reset
            op[(size_t)(s * TT + t) * HH] = sp;             // t=3 overwrites seed
        }
        d0 = d1;
        d1 = dn;
    }
    vfinal[tid] = v;
}

extern "C" void kernel_launch(void* const* d_in, const int* in_sizes, int n_in,
                              void* d_out, int out_size, void* d_ws, size_t ws_size,
                              hipStream_t stream) {
    const f4* x   = (const f4*)d_in[0];   // [B,S,I,H]
    const f4* enc = (const f4*)d_in[1];   // [I,H]
    float* out    = (float*)d_out;                        // [B,S*T,H] then [B,H]
    float* vfinal = out + (size_t)BB * SS * TT * HH;      // concatenated flat

    (void)d_ws; (void)ws_size;  // workspace intentionally unused

    {
        // one wave per row-pair: (B*S/2) waves * 64 lanes = 131072 threads
        const int nthreads = (BB * SS / 2) * 64;
        drive_kernel<<<nthreads / 256, 256, 0, stream>>>(x, enc, (f4*)out);
    }
    {
        const int n = BB * HH;                     // 32,768 threads
        lif_kernel<<<n / 64, 64, 0, stream>>>(out, vfinal);
    }
}